// Round 14
// baseline (2771.998 us; speedup 1.0000x reference)
//
#include <hip/hip_runtime.h>
#include <hip/hip_bf16.h>

typedef __attribute__((ext_vector_type(8))) short bf16x8;
typedef __attribute__((ext_vector_type(4))) float f32x4;
typedef __attribute__((ext_vector_type(4))) unsigned int u32x4;
typedef __attribute__((ext_vector_type(2))) unsigned int u32x2;
typedef unsigned short u16;
typedef unsigned int u32;

#define SENT 0x7FC07FC0u   // 2x bf16 NaN — unreachable as real h data

__device__ __forceinline__ u16 f2bf(float f) {
  union { float f; unsigned u; } v; v.f = f;
  unsigned r = v.u + 0x7FFFu + ((v.u >> 16) & 1u);   // RTNE
  return (u16)(r >> 16);
}

__device__ __forceinline__ float sigm_fast(float x) {
  return __builtin_amdgcn_rcpf(1.f + __expf(-x));
}
__device__ __forceinline__ float tanh_fast(float x) {
  x = fminf(fmaxf(x, -15.f), 15.f);
  float e = __expf(2.f * x);
  return (e - 1.f) * __builtin_amdgcn_rcpf(e + 1.f);
}

// ---- untracked (inline-asm) memory ops: caller owns the vmcnt ledger ----
__device__ __forceinline__ void ld_llc_b128(const u16* p, bf16x8& r) {  // coherent
  asm volatile("global_load_dwordx4 %0, %1, off sc0 sc1" : "=&v"(r) : "v"(p));
}
__device__ __forceinline__ void ld_g_b128(const u16* p, bf16x8& r) {    // cached
  asm volatile("global_load_dwordx4 %0, %1, off" : "=&v"(r) : "v"(p));
}
__device__ __forceinline__ void st_llc_b64(u16* p, u32x2 v) {           // coherent
  asm volatile("global_store_dwordx2 %0, %1, off sc0 sc1" :: "v"(p), "v"(v) : "memory");
}
__device__ __forceinline__ void st_g_b32(u32* p, u32 v) {               // cached
  asm volatile("global_store_dword %0, %1, off" :: "v"(p), "v"(v) : "memory");
}

// ---------------------------------------------------------------------------
// fold (all 4 gates, z = gate): Wt[(j*4+g)][k] = sum_m P[m][j]*(W[k][m]*cos(rx[m]))
// ---------------------------------------------------------------------------
__global__ __launch_bounds__(256) void fold_kernel(
    const float* __restrict__ W0, const float* __restrict__ rx0, const float* __restrict__ P0,
    const float* __restrict__ W1, const float* __restrict__ rx1, const float* __restrict__ P1,
    const float* __restrict__ W2, const float* __restrict__ rx2, const float* __restrict__ P2,
    const float* __restrict__ W3, const float* __restrict__ rx3, const float* __restrict__ P3,
    u16* __restrict__ Wt)
{
  const int g = blockIdx.z;
  const float* W  = (g == 0) ? W0  : (g == 1) ? W1  : (g == 2) ? W2  : W3;
  const float* rx = (g == 0) ? rx0 : (g == 1) ? rx1 : (g == 2) ? rx2 : rx3;
  const float* P  = (g == 0) ? P0  : (g == 1) ? P1  : (g == 2) ? P2  : P3;
  __shared__ __align__(16) float As[16][68];
  __shared__ __align__(16) float Bs[16][68];
  const int bk = blockIdx.x, bj = blockIdx.y;
  const int tid = threadIdx.x;
  const int tx = tid & 15, ty = tid >> 4;
  const int j0 = bj * 64, k0 = bk * 64;
  float acc[4][4] = {};
  for (int m0 = 0; m0 < 512; m0 += 16) {
#pragma unroll
    for (int l = 0; l < 4; ++l) {
      int lin = tid + 256 * l;
      int mm = lin >> 6, jr = lin & 63;
      As[mm][jr] = P[(m0 + mm) * 512 + j0 + jr];
      int kk = lin >> 4, mb = lin & 15;
      Bs[mb][kk] = W[(k0 + kk) * 512 + m0 + mb] * cosf(rx[m0 + mb]);
    }
    __syncthreads();
#pragma unroll
    for (int mm = 0; mm < 16; ++mm) {
      f32x4 a = *(const f32x4*)&As[mm][ty * 4];
      f32x4 b = *(const f32x4*)&Bs[mm][tx * 4];
#pragma unroll
      for (int i = 0; i < 4; ++i)
#pragma unroll
        for (int jj = 0; jj < 4; ++jj)
          acc[i][jj] += a[i] * b[jj];
    }
    __syncthreads();
  }
#pragma unroll
  for (int i = 0; i < 4; ++i) {
    int j = j0 + ty * 4 + i;
    size_t n = (size_t)(j * 4 + g);
    ushort4 w;
    w.x = f2bf(acc[i][0]); w.y = f2bf(acc[i][1]);
    w.z = f2bf(acc[i][2]); w.w = f2bf(acc[i][3]);
    *(ushort4*)(Wt + n * 1024 + k0 + tx * 4) = w;
  }
}

// bpn[j*4+g]; grid 32 = 4 gates x 8 j-blocks
__global__ __launch_bounds__(256) void fold_bias(
    const float* __restrict__ b0, const float* __restrict__ rx0, const float* __restrict__ P0,
    const float* __restrict__ b1, const float* __restrict__ rx1, const float* __restrict__ P1,
    const float* __restrict__ b2, const float* __restrict__ rx2, const float* __restrict__ P2,
    const float* __restrict__ b3, const float* __restrict__ rx3, const float* __restrict__ P3,
    float* __restrict__ bpn)
{
  const int g = blockIdx.x >> 3, jb = blockIdx.x & 7;
  const float* b  = (g == 0) ? b0  : (g == 1) ? b1  : (g == 2) ? b2  : b3;
  const float* rx = (g == 0) ? rx0 : (g == 1) ? rx1 : (g == 2) ? rx2 : rx3;
  const float* P  = (g == 0) ? P0  : (g == 1) ? P1  : (g == 2) ? P2  : P3;
  __shared__ float bc[512];
  __shared__ float red[4][65];
  const int tid = threadIdx.x;
  bc[tid] = b[tid] * cosf(rx[tid]);
  bc[tid + 256] = b[tid + 256] * cosf(rx[tid + 256]);
  __syncthreads();
  const int jl = tid & 63, msub = tid >> 6;
  const int j = jb * 64 + jl;
  float acc = 0.f;
  for (int m = msub * 128; m < msub * 128 + 128; ++m)
    acc += bc[m] * P[m * 512 + j];
  red[msub][jl] = acc;
  __syncthreads();
  if (msub == 0)
    bpn[j * 4 + g] = red[0][jl] + red[1][jl] + red[2][jl] + red[3][jl];
}

__global__ __launch_bounds__(256) void xcvt_kernel(
    const float* __restrict__ x, u16* __restrict__ xb)
{
  size_t i = (size_t)blockIdx.x * 256 + threadIdx.x;
  f32x4 v = *(const f32x4*)(x + i * 4);
  ushort4 w;
  w.x = f2bf(v[0]); w.y = f2bf(v[1]); w.z = f2bf(v[2]); w.w = f2bf(v[3]);
  *(ushort4*)(xb + i * 4) = w;
}

// sentinel-fill hslab (4 slabs), zero hz (fallback h) + cbuf, every launch
__global__ __launch_bounds__(256) void init_kernel(u32* hslab32, u32* hz32,
                                                   float* cbuf) {
  int i = blockIdx.x * 256 + threadIdx.x;      // 65536
  hslab32[i] = SENT;
  hslab32[i + 65536] = SENT;
  hz32[i] = 0;
  cbuf[i] = 0.f;
}

__global__ __launch_bounds__(256) void tail_kernel(
    const float* __restrict__ hlast, const float* __restrict__ c,
    float* __restrict__ hx, float* __restrict__ cx)
{
  int i = blockIdx.x * 256 + threadIdx.x;
  hx[i] = hlast[i];
  cx[i] = c[i];
}

// ---------------------------------------------------------------------------
// fallback single-step kernel (R1-proven)
// ---------------------------------------------------------------------------
__global__ __launch_bounds__(256) void step_kernel(
    const u16* __restrict__ xb_t, const u16* __restrict__ h_in,
    u16* __restrict__ h_out, const u16* __restrict__ Wt,
    const float* __restrict__ bpn, float* __restrict__ cbuf,
    float* __restrict__ out_t)
{
  __shared__ float pre_s[32][33];
  const int bid = blockIdx.x;
  const int mb = bid >> 6, nb = bid & 63;
  const int b0 = mb * 32, n0 = nb * 32;
  const int tid = threadIdx.x;
  const int wv = tid >> 6, lane = tid & 63;
  const int rt = wv >> 1, nt = wv & 1;
  const int l15 = lane & 15, kg = lane >> 4;
  const int brow = b0 + rt * 16 + l15;
  const int ncol = n0 + nt * 16 + l15;
  const u16* wrow = Wt + (size_t)ncol * 1024;
  const u16* xrow = xb_t + (size_t)brow * 512;
  const u16* hrow = h_in + (size_t)brow * 512;
  f32x4 acc = {0.f, 0.f, 0.f, 0.f};
#pragma unroll 8
  for (int kk = 0; kk < 32; ++kk) {
    const int kb = kk * 32 + kg * 8;
    bf16x8 bfrag = *(const bf16x8*)(wrow + kb);
    bf16x8 afrag;
    if (kb < 512) afrag = *(const bf16x8*)(xrow + kb);
    else          afrag = *(const bf16x8*)(hrow + (kb - 512));
    acc = __builtin_amdgcn_mfma_f32_16x16x32_bf16(afrag, bfrag, acc, 0, 0, 0);
  }
  const float bias = bpn[ncol];
#pragma unroll
  for (int q = 0; q < 4; ++q)
    pre_s[rt * 16 + kg * 4 + q][nt * 16 + l15] = acc[q] + bias;
  __syncthreads();
  const int bb = tid >> 3, jo = tid & 7;
  float pf = pre_s[bb][jo * 4 + 0];
  float pi = pre_s[bb][jo * 4 + 1];
  float pu = pre_s[bb][jo * 4 + 2];
  float po = pre_s[bb][jo * 4 + 3];
  float fg = 1.f / (1.f + __expf(-pf));
  float ig = 1.f / (1.f + __expf(-pi));
  float gg = tanhf(pu);
  float og = 1.f / (1.f + __expf(-po));
  size_t idx = (size_t)(b0 + bb) * 512 + (size_t)(nb * 8 + jo);
  float cv = fg * cbuf[idx] + ig * gg;
  cbuf[idx] = cv;
  float hv = og * tanhf(cv);
  out_t[idx] = hv;
  h_out[idx] = f2bf(hv);
}

// ---------------------------------------------------------------------------
// persistent recurrence v8: flagless sentinels + ZERO barriers.
// Each wave's 16x16 tile holds complete gate quads for its 16 rows -> the
// transpose + cell update are intra-wave (per-wave LDS patch, lgkmcnt only).
// Waves free-run; the sentinel poll enforces all ordering. Selective retry
// (per-lane stale bitmask) cuts poll traffic ~16x vs R13. Producer never
// waits: h-store fire-and-forget; reset issued after the poll so the first
// poll vmcnt(0) never waits on own stores.
// Slab rotation (R13-proven): read t%4, write (t+1)%4, reset (t+2)%4.
// ---------------------------------------------------------------------------
__global__ __launch_bounds__(256, 1) void qlstm_persistent(
    const u16* __restrict__ Xbf,    // [256][128][512] bf16
    u16* __restrict__ hslab,        // [4][128][512] bf16
    const u16* __restrict__ Wt,     // [2048][1024] bf16, n = j*4+g
    const float* __restrict__ bpn,  // [2048] f32
    float* __restrict__ out)        // [256][128][512] + hx + cx
{
  __shared__ float pre_s[4][16][17];
  const int bid = blockIdx.x;
  const int mb = bid & 3, nb = bid >> 2;     // group spread across XCDs
  const int b0 = mb * 32, n0 = nb * 32;
  const int tid = threadIdx.x;
  const int wv = tid >> 6, lane = tid & 63;
  const int rt = wv >> 1, nt = wv & 1;
  const int l15 = lane & 15, kg = lane >> 4;
  const int brow = b0 + rt * 16 + l15;
  const int ncol = n0 + nt * 16 + l15;

  // both W halves register-resident (128 VGPR)
  const u16* wrow = Wt + (size_t)ncol * 1024;
  bf16x8 warr[32];
#pragma unroll
  for (int kk = 0; kk < 32; ++kk)
    warr[kk] = *(const bf16x8*)(wrow + kk * 32 + kg * 8);
  const float bnc = bpn[ncol];

  // intra-wave cell mapping: lane (l15=row, kg=j-quad)
  const int jglob = nb * 8 + nt * 4 + kg;            // this lane's h column
  const size_t eidx = (size_t)brow * 512 + (size_t)jglob;
  const size_t hrow_off = (size_t)brow * 512 + (size_t)(nb * 8 + nt * 4);
  float cst = 0.f, hl = 0.f;

  // prologue: x-loads for t=0, drained once
  bf16x8 xf[16];
  {
    const u16* xr = Xbf + (size_t)brow * 512;
#pragma unroll
    for (int kk = 0; kk < 16; ++kk)
      ld_g_b128(xr + kk * 32 + kg * 8, xf[kk]);
    asm volatile("s_waitcnt vmcnt(0)" ::: "memory");
  }

  for (int t = 0; t < 256; ++t) {
    const u16* hr = hslab + (size_t)(t & 3) * 65536 + (size_t)brow * 512;
    bf16x8 hf[16];
    if (t > 0) {
#pragma unroll
      for (int kk = 0; kk < 16; ++kk)
        ld_llc_b128(hr + kk * 32 + kg * 8, hf[kk]);
    }
    // drain the 19 older ops [reset, h-store, out, x16]; keep 16 h-loads
    asm volatile("s_waitcnt vmcnt(16)" ::: "memory");
    __builtin_amdgcn_sched_barrier(0);

    // x-MFMAs from registers (overlap h-load latency)
    f32x4 ax0 = {0,0,0,0}, ax1 = {0,0,0,0};
#pragma unroll
    for (int kk = 0; kk < 16; kk += 2) {
      ax0 = __builtin_amdgcn_mfma_f32_16x16x32_bf16(xf[kk],     warr[kk],     ax0, 0, 0, 0);
      ax1 = __builtin_amdgcn_mfma_f32_16x16x32_bf16(xf[kk + 1], warr[kk + 1], ax1, 0, 0, 0);
    }

    // sentinel poll: selective retry on stale chunks only
    f32x4 ah0 = {0,0,0,0}, ah1 = {0,0,0,0};
    if (t > 0) {
      asm volatile("s_waitcnt vmcnt(0)" ::: "memory");
      __builtin_amdgcn_sched_barrier(0);
      int guard = 0;
      for (;;) {
        u32 stale = 0;
#pragma unroll
        for (int kk = 0; kk < 16; ++kk) {
          union { bf16x8 v; u32 d[4]; } u; u.v = hf[kk];
          u32 s = (u32)((u.d[0] == SENT) | (u.d[1] == SENT) |
                        (u.d[2] == SENT) | (u.d[3] == SENT));
          stale |= s << kk;
        }
        if (__all((int)(stale == 0))) break;
        if (++guard > 20000) break;            // bounded: fail loudly, no hang
        __builtin_amdgcn_s_sleep(1);
#pragma unroll
        for (int kk = 0; kk < 16; ++kk)
          if ((stale >> kk) & 1)
            ld_llc_b128(hr + kk * 32 + kg * 8, hf[kk]);
        asm volatile("s_waitcnt vmcnt(0)" ::: "memory");
        __builtin_amdgcn_sched_barrier(0);
      }
      __builtin_amdgcn_sched_barrier(0);
#pragma unroll
      for (int kk = 0; kk < 16; kk += 2) {
        ah0 = __builtin_amdgcn_mfma_f32_16x16x32_bf16(hf[kk],     warr[16 + kk],     ah0, 0, 0, 0);
        ah1 = __builtin_amdgcn_mfma_f32_16x16x32_bf16(hf[kk + 1], warr[16 + kk + 1], ah1, 0, 0, 0);
      }
    }
    f32x4 acc = (ax0 + ax1) + (ah0 + ah1);

    // reset own chunk in slab (t+2)&3 — after poll, so poll never waits on it;
    // ordered before next step's h-store by next step's poll vmcnt(0)
    {
      u32x2 sv = {SENT, SENT};
      if (kg == 0)
        st_llc_b64(hslab + (size_t)((t + 2) & 3) * 65536 + hrow_off, sv);
    }

    // intra-wave gate transpose (per-wave LDS patch, no barrier)
    // C/D layout: col = l15, row = kg*4+q
#pragma unroll
    for (int q = 0; q < 4; ++q)
      pre_s[wv][kg * 4 + q][l15] = acc[q] + bnc;
    asm volatile("s_waitcnt lgkmcnt(0)" ::: "memory");
    __builtin_amdgcn_sched_barrier(0);
    f32x4 g4 = *(const f32x4*)&pre_s[wv][l15][kg * 4];
    asm volatile("s_waitcnt lgkmcnt(0)" ::: "memory");
    __builtin_amdgcn_sched_barrier(0);

    // gates + cell update: lane owns (row=l15, j=jglob)
    cst = sigm_fast(g4[0]) * cst + sigm_fast(g4[1]) * tanh_fast(g4[2]);
    float hv = sigm_fast(g4[3]) * tanh_fast(cst);
    hl = hv;

    // shfl-gather 4 j's of this row -> one dwordx2, kg==0 lane stores
    u16 myh = f2bf(hv);
    u32 w  = (u32)myh | ((u32)(u16)__shfl_xor((int)(u32)myh, 16) << 16);
    u32 w2 = (u32)__shfl_xor((int)w, 32);
    if (kg == 0) {
      u32x2 hw = {w, w2};
      st_llc_b64(hslab + (size_t)((t + 1) & 3) * 65536 + hrow_off, hw);
    }

    // out store + x prefetch for t+1 (fire-and-forget, fly across the step)
    union { float f; u32 u; } ho; ho.f = hv;
    st_g_b32((u32*)(out + (size_t)t * 65536 + eidx), ho.u);
    if (t < 255) {
      const u16* xr = Xbf + (size_t)(t + 1) * 65536 + (size_t)brow * 512;
#pragma unroll
      for (int kk = 0; kk < 16; ++kk)
        ld_g_b128(xr + kk * 32 + kg * 8, xf[kk]);
    }
  }

  asm volatile("s_waitcnt vmcnt(0)" ::: "memory");
  out[(size_t)256 * 65536 + eidx] = hl;
  out[(size_t)256 * 65536 + 65536 + eidx] = cst;
}

// ---------------------------------------------------------------------------
extern "C" void kernel_launch(void* const* d_in, const int* in_sizes, int n_in,
                              void* d_out, int out_size, void* d_ws, size_t ws_size,
                              hipStream_t stream) {
  (void)in_sizes; (void)n_in; (void)out_size; (void)ws_size;
  const float* inp = (const float*)d_in[0];
  float* out = (float*)d_out;

  // ws: Xbf 33554432 | Wt 4194304 | bpn 8192 | hslab 524288 | hz 262144 | cbuf 262144
  char* base = (char*)d_ws;
  u16*   Xbf   = (u16*)base;
  u16*   Wt    = (u16*)(base + 33554432);
  float* bpn   = (float*)(base + 33554432 + 4194304);
  u16*   hslab = (u16*)(base + 33554432 + 4194304 + 8192);
  u16*   hz    = (u16*)(base + 33554432 + 4194304 + 8192 + 524288);
  float* cbuf  = (float*)(base + 33554432 + 4194304 + 8192 + 524288 + 262144);

  const float* W[4];  const float* b[4];  const float* rx[4];  const float* P[4];
  for (int g = 0; g < 4; ++g) {
    W[g]  = (const float*)d_in[1 + 4 * g];
    b[g]  = (const float*)d_in[2 + 4 * g];
    rx[g] = (const float*)d_in[3 + 4 * g];
    P[g]  = (const float*)d_in[4 + 4 * g];
  }
  fold_kernel<<<dim3(16, 8, 4), 256, 0, stream>>>(
      W[0], rx[0], P[0], W[1], rx[1], P[1],
      W[2], rx[2], P[2], W[3], rx[3], P[3], Wt);
  fold_bias<<<dim3(32), 256, 0, stream>>>(
      b[0], rx[0], P[0], b[1], rx[1], P[1],
      b[2], rx[2], P[2], b[3], rx[3], P[3], bpn);
  xcvt_kernel<<<16384, 256, 0, stream>>>(inp, Xbf);
  init_kernel<<<256, 256, 0, stream>>>((u32*)hslab, (u32*)hz, cbuf);

  void* args[5];
  const u16* Xbf_c = Xbf;
  const u16* Wt_c = Wt;
  const float* bpn_c = bpn;
  u16* hslab_p = hslab;
  float* out_p = out;
  args[0] = (void*)&Xbf_c;
  args[1] = (void*)&hslab_p;
  args[2] = (void*)&Wt_c;
  args[3] = (void*)&bpn_c;
  args[4] = (void*)&out_p;
  hipError_t e = hipLaunchCooperativeKernel((const void*)qlstm_persistent,
                                            dim3(256), dim3(256), args, 0, stream);
  if (e != hipSuccess) {
    for (int t = 0; t < 256; ++t) {
      const u16* xb_t  = Xbf + (size_t)t * 65536;
      const u16* h_in  = hz + (size_t)(t & 1) * 65536;
      u16*       h_oup = hz + (size_t)((t & 1) ^ 1) * 65536;
      float*     out_t = out + (size_t)t * 65536;
      step_kernel<<<256, 256, 0, stream>>>(xb_t, h_in, h_oup, Wt, bpn, cbuf, out_t);
    }
    tail_kernel<<<256, 256, 0, stream>>>(out + (size_t)255 * 65536, cbuf,
                                         out + (size_t)256 * 65536,
                                         out + (size_t)256 * 65536 + 65536);
  }
}

// Round 15
// 1524.977 us; speedup vs baseline: 1.8177x; 1.8177x over previous
//
#include <hip/hip_runtime.h>
#include <hip/hip_bf16.h>

typedef __attribute__((ext_vector_type(8))) short bf16x8;
typedef __attribute__((ext_vector_type(4))) float f32x4;
typedef __attribute__((ext_vector_type(4))) unsigned int u32x4;
typedef unsigned short u16;
typedef unsigned int u32;

#define SENT 0x7FC07FC0u   // 2x bf16 NaN — unreachable as real h data

__device__ __forceinline__ u16 f2bf(float f) {
  union { float f; unsigned u; } v; v.f = f;
  unsigned r = v.u + 0x7FFFu + ((v.u >> 16) & 1u);   // RTNE
  return (u16)(r >> 16);
}

__device__ __forceinline__ float sigm_fast(float x) {
  return __builtin_amdgcn_rcpf(1.f + __expf(-x));
}
__device__ __forceinline__ float tanh_fast(float x) {
  x = fminf(fmaxf(x, -15.f), 15.f);
  float e = __expf(2.f * x);
  return (e - 1.f) * __builtin_amdgcn_rcpf(e + 1.f);
}

// ---- untracked (inline-asm) memory ops: caller owns the vmcnt ledger ----
__device__ __forceinline__ void ld_llc_b128(const u16* p, bf16x8& r) {  // coherent
  asm volatile("global_load_dwordx4 %0, %1, off sc0 sc1" : "=&v"(r) : "v"(p));
}
__device__ __forceinline__ void ld_g_b128(const u16* p, bf16x8& r) {    // cached
  asm volatile("global_load_dwordx4 %0, %1, off" : "=&v"(r) : "v"(p));
}
__device__ __forceinline__ void st_llc_b128(u16* p, u32x4 v) {          // coherent
  asm volatile("global_store_dwordx4 %0, %1, off sc0 sc1" :: "v"(p), "v"(v) : "memory");
}
__device__ __forceinline__ void st_g_b32(u32* p, u32 v) {               // cached
  asm volatile("global_store_dword %0, %1, off" :: "v"(p), "v"(v) : "memory");
}

// ---------------------------------------------------------------------------
// fold (all 4 gates, z = gate): Wt[(j*4+g)][k] = sum_m P[m][j]*(W[k][m]*cos(rx[m]))
// ---------------------------------------------------------------------------
__global__ __launch_bounds__(256) void fold_kernel(
    const float* __restrict__ W0, const float* __restrict__ rx0, const float* __restrict__ P0,
    const float* __restrict__ W1, const float* __restrict__ rx1, const float* __restrict__ P1,
    const float* __restrict__ W2, const float* __restrict__ rx2, const float* __restrict__ P2,
    const float* __restrict__ W3, const float* __restrict__ rx3, const float* __restrict__ P3,
    u16* __restrict__ Wt)
{
  const int g = blockIdx.z;
  const float* W  = (g == 0) ? W0  : (g == 1) ? W1  : (g == 2) ? W2  : W3;
  const float* rx = (g == 0) ? rx0 : (g == 1) ? rx1 : (g == 2) ? rx2 : rx3;
  const float* P  = (g == 0) ? P0  : (g == 1) ? P1  : (g == 2) ? P2  : P3;
  __shared__ __align__(16) float As[16][68];
  __shared__ __align__(16) float Bs[16][68];
  const int bk = blockIdx.x, bj = blockIdx.y;
  const int tid = threadIdx.x;
  const int tx = tid & 15, ty = tid >> 4;
  const int j0 = bj * 64, k0 = bk * 64;
  float acc[4][4] = {};
  for (int m0 = 0; m0 < 512; m0 += 16) {
#pragma unroll
    for (int l = 0; l < 4; ++l) {
      int lin = tid + 256 * l;
      int mm = lin >> 6, jr = lin & 63;
      As[mm][jr] = P[(m0 + mm) * 512 + j0 + jr];
      int kk = lin >> 4, mb = lin & 15;
      Bs[mb][kk] = W[(k0 + kk) * 512 + m0 + mb] * cosf(rx[m0 + mb]);
    }
    __syncthreads();
#pragma unroll
    for (int mm = 0; mm < 16; ++mm) {
      f32x4 a = *(const f32x4*)&As[mm][ty * 4];
      f32x4 b = *(const f32x4*)&Bs[mm][tx * 4];
#pragma unroll
      for (int i = 0; i < 4; ++i)
#pragma unroll
        for (int jj = 0; jj < 4; ++jj)
          acc[i][jj] += a[i] * b[jj];
    }
    __syncthreads();
  }
#pragma unroll
  for (int i = 0; i < 4; ++i) {
    int j = j0 + ty * 4 + i;
    size_t n = (size_t)(j * 4 + g);
    ushort4 w;
    w.x = f2bf(acc[i][0]); w.y = f2bf(acc[i][1]);
    w.z = f2bf(acc[i][2]); w.w = f2bf(acc[i][3]);
    *(ushort4*)(Wt + n * 1024 + k0 + tx * 4) = w;
  }
}

// bpn[j*4+g]; grid 32 = 4 gates x 8 j-blocks
__global__ __launch_bounds__(256) void fold_bias(
    const float* __restrict__ b0, const float* __restrict__ rx0, const float* __restrict__ P0,
    const float* __restrict__ b1, const float* __restrict__ rx1, const float* __restrict__ P1,
    const float* __restrict__ b2, const float* __restrict__ rx2, const float* __restrict__ P2,
    const float* __restrict__ b3, const float* __restrict__ rx3, const float* __restrict__ P3,
    float* __restrict__ bpn)
{
  const int g = blockIdx.x >> 3, jb = blockIdx.x & 7;
  const float* b  = (g == 0) ? b0  : (g == 1) ? b1  : (g == 2) ? b2  : b3;
  const float* rx = (g == 0) ? rx0 : (g == 1) ? rx1 : (g == 2) ? rx2 : rx3;
  const float* P  = (g == 0) ? P0  : (g == 1) ? P1  : (g == 2) ? P2  : P3;
  __shared__ float bc[512];
  __shared__ float red[4][65];
  const int tid = threadIdx.x;
  bc[tid] = b[tid] * cosf(rx[tid]);
  bc[tid + 256] = b[tid + 256] * cosf(rx[tid + 256]);
  __syncthreads();
  const int jl = tid & 63, msub = tid >> 6;
  const int j = jb * 64 + jl;
  float acc = 0.f;
  for (int m = msub * 128; m < msub * 128 + 128; ++m)
    acc += bc[m] * P[m * 512 + j];
  red[msub][jl] = acc;
  __syncthreads();
  if (msub == 0)
    bpn[j * 4 + g] = red[0][jl] + red[1][jl] + red[2][jl] + red[3][jl];
}

__global__ __launch_bounds__(256) void xcvt_kernel(
    const float* __restrict__ x, u16* __restrict__ xb)
{
  size_t i = (size_t)blockIdx.x * 256 + threadIdx.x;
  f32x4 v = *(const f32x4*)(x + i * 4);
  ushort4 w;
  w.x = f2bf(v[0]); w.y = f2bf(v[1]); w.z = f2bf(v[2]); w.w = f2bf(v[3]);
  *(ushort4*)(xb + i * 4) = w;
}

// sentinel-fill hslab (4 slabs), zero hz (fallback h) + cbuf, every launch
__global__ __launch_bounds__(256) void init_kernel(u32* hslab32, u32* hz32,
                                                   float* cbuf) {
  int i = blockIdx.x * 256 + threadIdx.x;      // 65536
  hslab32[i] = SENT;
  hslab32[i + 65536] = SENT;
  hz32[i] = 0;
  cbuf[i] = 0.f;
}

__global__ __launch_bounds__(256) void tail_kernel(
    const float* __restrict__ hlast, const float* __restrict__ c,
    float* __restrict__ hx, float* __restrict__ cx)
{
  int i = blockIdx.x * 256 + threadIdx.x;
  hx[i] = hlast[i];
  cx[i] = c[i];
}

// ---------------------------------------------------------------------------
// fallback single-step kernel (R1-proven)
// ---------------------------------------------------------------------------
__global__ __launch_bounds__(256) void step_kernel(
    const u16* __restrict__ xb_t, const u16* __restrict__ h_in,
    u16* __restrict__ h_out, const u16* __restrict__ Wt,
    const float* __restrict__ bpn, float* __restrict__ cbuf,
    float* __restrict__ out_t)
{
  __shared__ float pre_s[32][33];
  const int bid = blockIdx.x;
  const int mb = bid >> 6, nb = bid & 63;
  const int b0 = mb * 32, n0 = nb * 32;
  const int tid = threadIdx.x;
  const int wv = tid >> 6, lane = tid & 63;
  const int rt = wv >> 1, nt = wv & 1;
  const int l15 = lane & 15, kg = lane >> 4;
  const int brow = b0 + rt * 16 + l15;
  const int ncol = n0 + nt * 16 + l15;
  const u16* wrow = Wt + (size_t)ncol * 1024;
  const u16* xrow = xb_t + (size_t)brow * 512;
  const u16* hrow = h_in + (size_t)brow * 512;
  f32x4 acc = {0.f, 0.f, 0.f, 0.f};
#pragma unroll 8
  for (int kk = 0; kk < 32; ++kk) {
    const int kb = kk * 32 + kg * 8;
    bf16x8 bfrag = *(const bf16x8*)(wrow + kb);
    bf16x8 afrag;
    if (kb < 512) afrag = *(const bf16x8*)(xrow + kb);
    else          afrag = *(const bf16x8*)(hrow + (kb - 512));
    acc = __builtin_amdgcn_mfma_f32_16x16x32_bf16(afrag, bfrag, acc, 0, 0, 0);
  }
  const float bias = bpn[ncol];
#pragma unroll
  for (int q = 0; q < 4; ++q)
    pre_s[rt * 16 + kg * 4 + q][nt * 16 + l15] = acc[q] + bias;
  __syncthreads();
  const int bb = tid >> 3, jo = tid & 7;
  float pf = pre_s[bb][jo * 4 + 0];
  float pi = pre_s[bb][jo * 4 + 1];
  float pu = pre_s[bb][jo * 4 + 2];
  float po = pre_s[bb][jo * 4 + 3];
  float fg = 1.f / (1.f + __expf(-pf));
  float ig = 1.f / (1.f + __expf(-pi));
  float gg = tanhf(pu);
  float og = 1.f / (1.f + __expf(-po));
  size_t idx = (size_t)(b0 + bb) * 512 + (size_t)(nb * 8 + jo);
  float cv = fg * cbuf[idx] + ig * gg;
  cbuf[idx] = cv;
  float hv = og * tanhf(cv);
  out_t[idx] = hv;
  h_out[idx] = f2bf(hv);
}

// ---------------------------------------------------------------------------
// persistent recurrence v9: sentinel detection + barrier-synced waves.
// R12 wave mapping + ONE barrier/step (pre_s double-buffered), R13 4-slab
// sentinel rotation + 16B packed h-stores, R14 selective retry.
// Chain: fire-and-forget h-store (tau) -> combined load+validate (tau, the
// poll IS the load) -> rare selective retries. No flags, no drains.
// Reset(t+2 slab) ordering rides the detection vmcnt(0) (R13-proven).
// ---------------------------------------------------------------------------
__global__ __launch_bounds__(256, 1) void qlstm_persistent(
    const u16* __restrict__ Xbf,    // [256][128][512] bf16
    u16* __restrict__ hslab,        // [4][128][512] bf16
    const u16* __restrict__ Wt,     // [2048][1024] bf16, n = j*4+g
    const float* __restrict__ bpn,  // [2048] f32
    float* __restrict__ out)        // [256][128][512] + hx + cx
{
  __shared__ float pre_s[2][32][33];
  const int bid = blockIdx.x;
  const int mb = bid & 3, nb = bid >> 2;     // group spread across XCDs
  const int b0 = mb * 32, n0 = nb * 32;
  const int tid = threadIdx.x;
  const int wv = tid >> 6, lane = tid & 63;
  const int rt = wv >> 1, nt = wv & 1;
  const int l15 = lane & 15, kg = lane >> 4;
  const int brow = b0 + rt * 16 + l15;
  const int ncol = n0 + nt * 16 + l15;

  // both W halves register-resident (128 VGPR)
  const u16* wrow = Wt + (size_t)ncol * 1024;
  bf16x8 warr[32];
#pragma unroll
  for (int kk = 0; kk < 32; ++kk)
    warr[kk] = *(const bf16x8*)(wrow + kk * 32 + kg * 8);
  const float bnc = bpn[ncol];

  // cell thread mapping (spans waves, intra-wave shfl-pack works per 8 lanes)
  const int bb = tid >> 3, jo = tid & 7;
  const size_t eidx = (size_t)(b0 + bb) * 512 + (size_t)(nb * 8 + jo);
  const bool pst = ((tid & 7) == 0);                 // chunk-store thread
  const size_t prow_off = (size_t)(b0 + (tid >> 3)) * 512 + (size_t)(nb * 8);
  const u32x4 sentv = {SENT, SENT, SENT, SENT};
  float cst = 0.f, hl = 0.f;

  // prologue: x-loads for t=0, drained once
  bf16x8 xf[16];
  {
    const u16* xr = Xbf + (size_t)brow * 512;
#pragma unroll
    for (int kk = 0; kk < 16; ++kk)
      ld_g_b128(xr + kk * 32 + kg * 8, xf[kk]);
    asm volatile("s_waitcnt vmcnt(0)" ::: "memory");
  }

  for (int t = 0; t < 256; ++t) {
    // ---- x-MFMAs from registers (x landed: drained below before use of hf;
    //      for t==0 we drained in prologue) ----
    f32x4 ax0 = {0,0,0,0}, ax1 = {0,0,0,0};

    // ---- sentinel detection: load h chunks, validate, selective retry ----
    bf16x8 hf[16];
    f32x4 ah0 = {0,0,0,0}, ah1 = {0,0,0,0};
    if (t > 0) {
      const u16* hr = hslab + (size_t)(t & 3) * 65536 + (size_t)brow * 512;
#pragma unroll
      for (int kk = 0; kk < 16; ++kk)
        ld_llc_b128(hr + kk * 32 + kg * 8, hf[kk]);

      // overlap h-load latency with x-MFMAs (x is in registers; the loads
      // above are untracked so MFMAs won't be reordered past the waitcnt)
#pragma unroll
      for (int kk = 0; kk < 16; kk += 2) {
        ax0 = __builtin_amdgcn_mfma_f32_16x16x32_bf16(xf[kk],     warr[kk],     ax0, 0, 0, 0);
        ax1 = __builtin_amdgcn_mfma_f32_16x16x32_bf16(xf[kk + 1], warr[kk + 1], ax1, 0, 0, 0);
      }

      asm volatile("s_waitcnt vmcnt(0)" ::: "memory");  // drains everything
      __builtin_amdgcn_sched_barrier(0);
      int guard = 0;
      for (;;) {
        u32 stale = 0;
#pragma unroll
        for (int kk = 0; kk < 16; ++kk) {
          union { bf16x8 v; u32 d[4]; } u; u.v = hf[kk];
          u32 s = (u32)((u.d[0] == SENT) | (u.d[1] == SENT) |
                        (u.d[2] == SENT) | (u.d[3] == SENT));
          stale |= s << kk;
        }
        if (__all((int)(stale == 0))) break;
        if (++guard > 10000) break;            // bounded: fail loudly, no hang
        __builtin_amdgcn_s_sleep(1);
#pragma unroll
        for (int kk = 0; kk < 16; ++kk)
          if ((stale >> kk) & 1)
            ld_llc_b128(hr + kk * 32 + kg * 8, hf[kk]);
        asm volatile("s_waitcnt vmcnt(0)" ::: "memory");
        __builtin_amdgcn_sched_barrier(0);
      }
      __builtin_amdgcn_sched_barrier(0);
#pragma unroll
      for (int kk = 0; kk < 16; kk += 2) {
        ah0 = __builtin_amdgcn_mfma_f32_16x16x32_bf16(hf[kk],     warr[16 + kk],     ah0, 0, 0, 0);
        ah1 = __builtin_amdgcn_mfma_f32_16x16x32_bf16(hf[kk + 1], warr[16 + kk + 1], ah1, 0, 0, 0);
      }
    } else {
#pragma unroll
      for (int kk = 0; kk < 16; kk += 2) {
        ax0 = __builtin_amdgcn_mfma_f32_16x16x32_bf16(xf[kk],     warr[kk],     ax0, 0, 0, 0);
        ax1 = __builtin_amdgcn_mfma_f32_16x16x32_bf16(xf[kk + 1], warr[kk + 1], ax1, 0, 0, 0);
      }
    }
    f32x4 acc = (ax0 + ax1) + (ah0 + ah1);

    // ---- reset own chunk in slab (t+2)&3 (fire-and-forget; next step's
    //      detection vmcnt(0) orders it before the (t+1)-step h-store) ----
    if (pst)
      st_llc_b128(hslab + (size_t)((t + 2) & 3) * 65536 + prow_off, sentv);

    // ---- LDS gate exchange, double-buffered; ONE barrier per step ----
    // C/D layout: col = lane&15, row = (lane>>4)*4 + q
#pragma unroll
    for (int q = 0; q < 4; ++q)
      pre_s[t & 1][rt * 16 + kg * 4 + q][nt * 16 + l15] = acc[q] + bnc;
    asm volatile("s_waitcnt lgkmcnt(0)" ::: "memory");
    __builtin_amdgcn_sched_barrier(0);
    __builtin_amdgcn_s_barrier();
    asm volatile("" ::: "memory");

    // ---- gates + cell update ----
    float pf = pre_s[t & 1][bb][jo * 4 + 0];
    float pi = pre_s[t & 1][bb][jo * 4 + 1];
    float pu = pre_s[t & 1][bb][jo * 4 + 2];
    float po = pre_s[t & 1][bb][jo * 4 + 3];
    cst = sigm_fast(pf) * cst + sigm_fast(pi) * tanh_fast(pu);
    float hv = sigm_fast(po) * tanh_fast(cst);
    hl = hv;

    // ---- fire-and-forget packed h-store (16B per row-chunk) ----
    u16 myh = f2bf(hv);
    u32 w  = (u32)myh | ((u32)(u16)__shfl_xor((int)(u32)myh, 1) << 16);
    u32 d1 = (u32)__shfl_xor((int)w, 2);
    u32 d2 = (u32)__shfl_xor((int)w, 4);
    u32 d3 = (u32)__shfl_xor((int)w, 6);
    if (pst) {
      u32x4 hw = {w, d1, d2, d3};
      st_llc_b128(hslab + (size_t)((t + 1) & 3) * 65536 + prow_off, hw);
    }

    // ---- out store + x prefetch for t+1 (fire-and-forget) ----
    union { float f; u32 u; } ho; ho.f = hv;
    st_g_b32((u32*)(out + (size_t)t * 65536 + eidx), ho.u);
    if (t < 255) {
      const u16* xr = Xbf + (size_t)(t + 1) * 65536 + (size_t)brow * 512;
#pragma unroll
      for (int kk = 0; kk < 16; ++kk)
        ld_g_b128(xr + kk * 32 + kg * 8, xf[kk]);
    }
  }

  asm volatile("s_waitcnt vmcnt(0)" ::: "memory");
  out[(size_t)256 * 65536 + eidx] = hl;
  out[(size_t)256 * 65536 + 65536 + eidx] = cst;
}

// ---------------------------------------------------------------------------
extern "C" void kernel_launch(void* const* d_in, const int* in_sizes, int n_in,
                              void* d_out, int out_size, void* d_ws, size_t ws_size,
                              hipStream_t stream) {
  (void)in_sizes; (void)n_in; (void)out_size; (void)ws_size;
  const float* inp = (const float*)d_in[0];
  float* out = (float*)d_out;

  // ws: Xbf 33554432 | Wt 4194304 | bpn 8192 | hslab 524288 | hz 262144 | cbuf 262144
  char* base = (char*)d_ws;
  u16*   Xbf   = (u16*)base;
  u16*   Wt    = (u16*)(base + 33554432);
  float* bpn   = (float*)(base + 33554432 + 4194304);
  u16*   hslab = (u16*)(base + 33554432 + 4194304 + 8192);
  u16*   hz    = (u16*)(base + 33554432 + 4194304 + 8192 + 524288);
  float* cbuf  = (float*)(base + 33554432 + 4194304 + 8192 + 524288 + 262144);

  const float* W[4];  const float* b[4];  const float* rx[4];  const float* P[4];
  for (int g = 0; g < 4; ++g) {
    W[g]  = (const float*)d_in[1 + 4 * g];
    b[g]  = (const float*)d_in[2 + 4 * g];
    rx[g] = (const float*)d_in[3 + 4 * g];
    P[g]  = (const float*)d_in[4 + 4 * g];
  }
  fold_kernel<<<dim3(16, 8, 4), 256, 0, stream>>>(
      W[0], rx[0], P[0], W[1], rx[1], P[1],
      W[2], rx[2], P[2], W[3], rx[3], P[3], Wt);
  fold_bias<<<dim3(32), 256, 0, stream>>>(
      b[0], rx[0], P[0], b[1], rx[1], P[1],
      b[2], rx[2], P[2], b[3], rx[3], P[3], bpn);
  xcvt_kernel<<<16384, 256, 0, stream>>>(inp, Xbf);
  init_kernel<<<256, 256, 0, stream>>>((u32*)hslab, (u32*)hz, cbuf);

  void* args[5];
  const u16* Xbf_c = Xbf;
  const u16* Wt_c = Wt;
  const float* bpn_c = bpn;
  u16* hslab_p = hslab;
  float* out_p = out;
  args[0] = (void*)&Xbf_c;
  args[1] = (void*)&hslab_p;
  args[2] = (void*)&Wt_c;
  args[3] = (void*)&bpn_c;
  args[4] = (void*)&out_p;
  hipError_t e = hipLaunchCooperativeKernel((const void*)qlstm_persistent,
                                            dim3(256), dim3(256), args, 0, stream);
  if (e != hipSuccess) {
    for (int t = 0; t < 256; ++t) {
      const u16* xb_t  = Xbf + (size_t)t * 65536;
      const u16* h_in  = hz + (size_t)(t & 1) * 65536;
      u16*       h_oup = hz + (size_t)((t & 1) ^ 1) * 65536;
      float*     out_t = out + (size_t)t * 65536;
      step_kernel<<<256, 256, 0, stream>>>(xb_t, h_in, h_oup, Wt, bpn, cbuf, out_t);
    }
    tail_kernel<<<256, 256, 0, stream>>>(out + (size_t)255 * 65536, cbuf,
                                         out + (size_t)256 * 65536,
                                         out + (size_t)256 * 65536 + 65536);
  }
}